// Round 2
// baseline (1949.650 us; speedup 1.0000x reference)
//
#include <hip/hip_runtime.h>

// KrausRK4: B=4096 batches of 64x64 fp32 density matrices, K=4 jump ops.
// Plan: 44 matmuls (64^3) per batch, all in LDS, one block per batch.

#define LDA 68            // padded row stride (floats): 16B-aligned, bank-spread
#define MS  (64 * LDA)    // 4352 floats per matrix buffer

union F4 { float4 v; float f[4]; };

__device__ __forceinline__ void load_mat(float* __restrict__ dst,
                                         const float* __restrict__ src, int tid) {
#pragma unroll
  for (int it = 0; it < 4; ++it) {
    int w = 4 * tid + 1024 * it;
    int r = w >> 6, c = w & 63;
    *(float4*)(dst + r * LDA + c) = *(const float4*)(src + w);
  }
}

__device__ __forceinline__ void store_mat(float* __restrict__ dst,
                                          const float* __restrict__ src, int tid) {
#pragma unroll
  for (int it = 0; it < 4; ++it) {
    int w = 4 * tid + 1024 * it;
    int r = w >> 6, c = w & 63;
    *(float4*)(dst + w) = *(const float4*)(src + r * LDA + c);
  }
}

// Stage 64x64 operator transposed into LDS: dst[c][r] = src[r][c]
__device__ __forceinline__ void stage_T(float* __restrict__ dst,
                                        const float* __restrict__ src, int tid) {
#pragma unroll
  for (int it = 0; it < 4; ++it) {
    int w = 4 * tid + 1024 * it;
    int r = w >> 6, c = w & 63;
    F4 v; v.v = *(const float4*)(src + w);
#pragma unroll
    for (int u = 0; u < 4; ++u) dst[(c + u) * LDA + r] = v.f[u];
  }
}

// D = A + s*B (elementwise, LDS); safe if D aliases A or B
__device__ __forceinline__ void axpy_mat(float* __restrict__ D,
                                         const float* __restrict__ A, float s,
                                         const float* __restrict__ Bm, int tid) {
#pragma unroll
  for (int it = 0; it < 4; ++it) {
    int w = 4 * tid + 1024 * it;
    int r = w >> 6, c = w & 63;
    int a = r * LDA + c;
    F4 va, vb, o;
    va.v = *(const float4*)(A + a);
    vb.v = *(const float4*)(Bm + a);
#pragma unroll
    for (int u = 0; u < 4; ++u) o.f[u] = va.f[u] + s * vb.f[u];
    *(float4*)(D + a) = o.v;
  }
}

// C = (accum ? C : 0) + alpha * (At^T @ Bm)   i.e. C[i][j] += sum_k At[k][i]*Bm[k][j]
__device__ __forceinline__ void mm_TN(float* __restrict__ C,
                                      const float* __restrict__ At,
                                      const float* __restrict__ Bm,
                                      float alpha, bool accum, int tx, int ty) {
  float acc[4][4] = {};
#pragma unroll 4
  for (int k = 0; k < 64; ++k) {
    F4 a, b;
    a.v = *(const float4*)(At + k * LDA + 4 * ty);
    b.v = *(const float4*)(Bm + k * LDA + 4 * tx);
#pragma unroll
    for (int di = 0; di < 4; ++di)
#pragma unroll
      for (int dj = 0; dj < 4; ++dj)
        acc[di][dj] += a.f[di] * b.f[dj];
  }
#pragma unroll
  for (int di = 0; di < 4; ++di) {
    float* cp = C + (4 * ty + di) * LDA + 4 * tx;
    F4 o;
    if (accum) {
      F4 old; old.v = *(const float4*)cp;
#pragma unroll
      for (int dj = 0; dj < 4; ++dj) o.f[dj] = old.f[dj] + alpha * acc[di][dj];
    } else {
#pragma unroll
      for (int dj = 0; dj < 4; ++dj) o.f[dj] = alpha * acc[di][dj];
    }
    *(float4*)cp = o.v;
  }
}

// C = (accum ? C : 0) + alpha * (A @ Bm)      i.e. C[i][j] += sum_k A[i][k]*Bm[k][j]
__device__ __forceinline__ void mm_NN(float* __restrict__ C,
                                      const float* __restrict__ A,
                                      const float* __restrict__ Bm,
                                      float alpha, bool accum, int tx, int ty) {
  float acc[4][4] = {};
#pragma unroll 2
  for (int k = 0; k < 64; k += 4) {
    F4 ar[4], br[4];
#pragma unroll
    for (int di = 0; di < 4; ++di)
      ar[di].v = *(const float4*)(A + (4 * ty + di) * LDA + k);
#pragma unroll
    for (int dk = 0; dk < 4; ++dk)
      br[dk].v = *(const float4*)(Bm + (k + dk) * LDA + 4 * tx);
#pragma unroll
    for (int di = 0; di < 4; ++di)
#pragma unroll
      for (int dk = 0; dk < 4; ++dk)
#pragma unroll
        for (int dj = 0; dj < 4; ++dj)
          acc[di][dj] += ar[di].f[dk] * br[dk].f[dj];
  }
#pragma unroll
  for (int di = 0; di < 4; ++di) {
    float* cp = C + (4 * ty + di) * LDA + 4 * tx;
    F4 o;
    if (accum) {
      F4 old; old.v = *(const float4*)cp;
#pragma unroll
      for (int dj = 0; dj < 4; ++dj) o.f[dj] = old.f[dj] + alpha * acc[di][dj];
    } else {
#pragma unroll
      for (int dj = 0; dj < 4; ++dj) o.f[dj] = alpha * acc[di][dj];
    }
    *(float4*)cp = o.v;
  }
}

// ---------------- Um1 = U1 @ inv(Um) via Gauss-Jordan w/ partial pivoting ----
__global__ __launch_bounds__(256) void kraus_invert(
    const float* __restrict__ U1, const float* __restrict__ Um,
    float* __restrict__ Um1) {
  __shared__ float M[64][66];
  __shared__ float X[64][66];
  __shared__ int s_piv;
  int tid = threadIdx.x;

#pragma unroll
  for (int it = 0; it < 16; ++it) {
    int idx = tid + 256 * it;
    int r = idx >> 6, c = idx & 63;
    M[r][c] = Um[idx];
    X[r][c] = (r == c) ? 1.0f : 0.0f;
  }
  __syncthreads();

  for (int k = 0; k < 64; ++k) {
    // partial pivot: argmax over rows k..63 of |M[r][k]| (wave 0 only)
    if (tid < 64) {
      float v = (tid >= k) ? fabsf(M[tid][k]) : -1.0f;
      int idx = tid;
      for (int off = 32; off; off >>= 1) {
        float ov = __shfl_down(v, off);
        int oi = __shfl_down(idx, off);
        if (ov > v) { v = ov; idx = oi; }
      }
      if (tid == 0) s_piv = idx;
    }
    __syncthreads();
    int p = s_piv;
    if (p != k && tid < 64) {
      float t1 = M[k][tid]; M[k][tid] = M[p][tid]; M[p][tid] = t1;
      float t2 = X[k][tid]; X[k][tid] = X[p][tid]; X[p][tid] = t2;
    }
    __syncthreads();
    float inv_pv = 1.0f / M[k][k];
    __syncthreads();
    if (tid < 64) { M[k][tid] *= inv_pv; X[k][tid] *= inv_pv; }
    __syncthreads();
    int r = tid & 63;
    int q = tid >> 6;
    float f = M[r][k];
    __syncthreads();
    if (r != k) {
#pragma unroll
      for (int cc = 0; cc < 16; ++cc) {
        int c = q * 16 + cc;
        M[r][c] -= f * M[k][c];
        X[r][c] -= f * X[k][c];
      }
    }
    __syncthreads();
  }

  // Um1 = U1 @ X
  for (int it = 0; it < 16; ++it) {
    int idx = tid + 256 * it;
    int i = idx >> 6, j = idx & 63;
    float s = 0.0f;
#pragma unroll 4
    for (int k = 0; k < 64; ++k) s += U1[i * 64 + k] * X[k][j];
    Um1[idx] = s;
  }
}

// ---------------- main kernel: one block per batch item ----------------------
__global__ __launch_bounds__(256) void kraus_main(
    const float* __restrict__ rho0g, const float* __restrict__ U1g,
    const float* __restrict__ Umg, const float* __restrict__ Ls0,
    const float* __restrict__ Lsmid, const float* __restrict__ Ls1,
    const float* __restrict__ dtp, const float* __restrict__ Um1g,
    float* __restrict__ outg) {
  __shared__ float lds[7 * MS];  // B0..B4, TMP, OP = 121856 B
  float* B0 = lds + 0 * MS;   // rho0, later J2
  float* B1 = lds + 1 * MS;   // J0 -> T -> rho2 -> rho3 -> JJ
  float* B2 = lds + 2 * MS;   // output accumulator
  float* B3 = lds + 3 * MS;   // S -> J3
  float* B4 = lds + 4 * MS;   // P -> rho4
  float* TMP = lds + 5 * MS;
  float* OP = lds + 6 * MS;   // staged transposed operator

  const int tid = threadIdx.x;
  const int tx = tid & 15, ty = tid >> 4;
  const float dt = dtp[0];
  const size_t b = blockIdx.x;
  const float* rho = rho0g + b * 4096;

  load_mat(B0, rho, tid);

  // J0 -> B1  (jump(Ls0, rho0))
  for (int k = 0; k < 4; ++k) {
    __syncthreads();
    stage_T(OP, Ls0 + k * 4096, tid);
    __syncthreads();
    mm_TN(TMP, OP, B0, 1.0f, false, tx, ty);   // TMP = L @ rho0
    __syncthreads();
    mm_NN(B1, TMP, OP, 1.0f, k > 0, tx, ty);   // B1 += TMP @ L^T
  }

  // ACC(B2) = dt/6 * sandwich(U1, J0)
  __syncthreads();
  stage_T(OP, U1g, tid);
  __syncthreads();
  mm_TN(TMP, OP, B1, 1.0f, false, tx, ty);
  __syncthreads();
  mm_NN(B2, TMP, OP, dt / 6.0f, false, tx, ty);
  __syncthreads();

  // T = rho0 + 0.5dt*J0 -> B1
  axpy_mat(B1, B0, 0.5f * dt, B1, tid);

  // rho2 = sandwich(Um, T) -> B1
  __syncthreads();
  stage_T(OP, Umg, tid);
  __syncthreads();
  mm_TN(TMP, OP, B1, 1.0f, false, tx, ty);
  __syncthreads();
  mm_NN(B1, TMP, OP, 1.0f, false, tx, ty);
  __syncthreads();

  // S = sandwich(Um, rho0) -> B3   (OP still holds Um^T)
  mm_TN(TMP, OP, B0, 1.0f, false, tx, ty);
  __syncthreads();
  mm_NN(B3, TMP, OP, 1.0f, false, tx, ty);

  // P = sandwich(U1, rho0) -> B4; ACC += P
  __syncthreads();
  stage_T(OP, U1g, tid);
  __syncthreads();
  mm_TN(TMP, OP, B0, 1.0f, false, tx, ty);
  __syncthreads();
  mm_NN(B4, TMP, OP, 1.0f, false, tx, ty);
  __syncthreads();
  axpy_mat(B2, B2, 1.0f, B4, tid);

  // J2 -> B0 (rho0 dead)
  for (int k = 0; k < 4; ++k) {
    __syncthreads();
    stage_T(OP, Lsmid + k * 4096, tid);
    __syncthreads();
    mm_TN(TMP, OP, B1, 1.0f, false, tx, ty);   // L @ rho2
    __syncthreads();
    mm_NN(B0, TMP, OP, 1.0f, k > 0, tx, ty);
  }

  // rho3 = S + 0.5dt*J2 -> B1
  __syncthreads();
  axpy_mat(B1, B3, 0.5f * dt, B0, tid);

  // J3 -> B3 (S dead)
  for (int k = 0; k < 4; ++k) {
    __syncthreads();
    stage_T(OP, Lsmid + k * 4096, tid);
    __syncthreads();
    mm_TN(TMP, OP, B1, 1.0f, false, tx, ty);   // L @ rho3
    __syncthreads();
    mm_NN(B3, TMP, OP, 1.0f, k > 0, tx, ty);
  }

  // JJ = J2 + J3 -> B1 (rho3 dead)
  __syncthreads();
  axpy_mat(B1, B0, 1.0f, B3, tid);

  // ACC += dt/3 * sandwich(Um1, JJ)
  __syncthreads();
  stage_T(OP, Um1g, tid);
  __syncthreads();
  mm_TN(TMP, OP, B1, 1.0f, false, tx, ty);
  __syncthreads();
  mm_NN(B2, TMP, OP, dt / 3.0f, true, tx, ty);
  __syncthreads();

  // rho4 = P + dt * sandwich(Um1, J3) -> B4   (OP still holds Um1^T)
  mm_TN(TMP, OP, B3, 1.0f, false, tx, ty);
  __syncthreads();
  mm_NN(B4, TMP, OP, dt, true, tx, ty);        // B4 = P + dt*(...)

  // ACC += dt/6 * jump(Ls1, rho4)
  for (int k = 0; k < 4; ++k) {
    __syncthreads();
    stage_T(OP, Ls1 + k * 4096, tid);
    __syncthreads();
    mm_TN(TMP, OP, B4, 1.0f, false, tx, ty);   // L @ rho4
    __syncthreads();
    mm_NN(B2, TMP, OP, dt / 6.0f, true, tx, ty);
  }

  __syncthreads();
  store_mat(outg + b * 4096, B2, tid);
}

extern "C" void kernel_launch(void* const* d_in, const int* in_sizes, int n_in,
                              void* d_out, int out_size, void* d_ws, size_t ws_size,
                              hipStream_t stream) {
  const float* rho0 = (const float*)d_in[0];
  const float* U1 = (const float*)d_in[1];
  const float* Um = (const float*)d_in[2];
  const float* Ls0 = (const float*)d_in[3];
  const float* Lsmid = (const float*)d_in[4];
  const float* Ls1 = (const float*)d_in[5];
  const float* dtp = (const float*)d_in[6];
  float* out = (float*)d_out;
  float* Um1 = (float*)d_ws;  // 64*64 floats scratch

  const int B = in_sizes[0] >> 12;  // /4096

  kraus_invert<<<1, 256, 0, stream>>>(U1, Um, Um1);
  kraus_main<<<B, 256, 0, stream>>>(rho0, U1, Um, Ls0, Lsmid, Ls1, dtp, Um1, out);
}

// Round 3
// 257.757 us; speedup vs baseline: 7.5639x; 7.5639x over previous
//
#include <hip/hip_runtime.h>

// KrausRK4 via bf16 MFMA: B=4096 batches, 64x64, K=4.
// All per-batch intermediates stored TRANSPOSED (hat(X)=X^T) as bf16 in LDS;
// MFMA primitive computes C = P @ Q^T with both operands read row-contiguous.
// Operators prepacked (bf16, fragment-major) in d_ws, staged per-phase to LDS.

typedef __attribute__((ext_vector_type(16))) float f32x16;
typedef __attribute__((ext_vector_type(8))) __bf16 bf16x8;
typedef __attribute__((ext_vector_type(4))) unsigned int u32x4;

#define PITCH 144                 // bytes per LDS matrix row (72 bf16, 64 used)
#define MATB  9216                // 64 * PITCH
#define OPA_B 32768               // 4 operator slots x 8KB
#define LDS_TOTAL (OPA_B + 5 * MATB)   // 78848 B -> 2 blocks/CU

__device__ __forceinline__ unsigned short bf16rne(float x) {
  unsigned u = __builtin_bit_cast(unsigned, x);
  return (unsigned short)((u + 0x7FFFu + ((u >> 16) & 1u)) >> 16);
}
__device__ __forceinline__ float bflo(unsigned u) {
  return __builtin_bit_cast(float, u << 16);
}
__device__ __forceinline__ float bfhi(unsigned u) {
  return __builtin_bit_cast(float, u & 0xFFFF0000u);
}

// acc += P @ Q^T over K=64 (4 MFMA k-steps). As/Bs = byte stride per k-step:
// 1024 for operator fragment layout, 32 for LDS row-major matrices.
__device__ __forceinline__ void mm4(f32x16& acc, const char* P, int As,
                                    const char* Q, int Bs) {
#pragma unroll
  for (int s = 0; s < 4; ++s) {
    bf16x8 a = *(const bf16x8*)(P + s * As);
    bf16x8 b = *(const bf16x8*)(Q + s * Bs);
    acc = __builtin_amdgcn_mfma_f32_32x32x16_bf16(a, b, acc, 0, 0, 0);
  }
}

// write 32x32 tile (C/D layout: col=lane&31, row=(r&3)+8*(r>>2)+4*(lane>>5))
// dst = matrix base + per-thread tile offset (precomputed)
__device__ __forceinline__ void wtile(char* dst, const f32x16& v) {
#pragma unroll
  for (int r = 0; r < 16; ++r) {
    int row = (r & 3) + 8 * (r >> 2);
    *(unsigned short*)(dst + row * PITCH) = bf16rne(v[r]);
  }
}

__device__ __forceinline__ void wtile_rmw(char* dst, const f32x16& v, float s) {
#pragma unroll
  for (int r = 0; r < 16; ++r) {
    int row = (r & 3) + 8 * (r >> 2);
    unsigned short* p = (unsigned short*)(dst + row * PITCH);
    float old = bflo((unsigned)*p);
    *p = bf16rne(old + s * v[r]);
  }
}

// D = A + s*B elementwise over whole padded matrix (2304 u32 = 4608 bf16)
__device__ __forceinline__ void axpy(char* D, const char* A, float s,
                                     const char* B, int tid) {
#pragma unroll
  for (int j = 0; j < 9; ++j) {
    int off = (tid + 256 * j) * 4;
    unsigned a = *(const unsigned*)(A + off);
    unsigned b = *(const unsigned*)(B + off);
    float lo = bflo(a) + s * bflo(b);
    float hi = bfhi(a) + s * bfhi(b);
    *(unsigned*)(D + off) = (unsigned)bf16rne(lo) | ((unsigned)bf16rne(hi) << 16);
  }
}

// copy nops x 8KB prepacked operator fragments global -> LDS (linear)
__device__ __forceinline__ void stage_ops(char* ldsA, const char* g, int nops,
                                          int tid) {
  for (int o = 0; o < nops; ++o)
#pragma unroll
    for (int j = 0; j < 2; ++j) {
      int off = o * 8192 + j * 4096 + tid * 16;
      *(u32x4*)(ldsA + off) = *(const u32x4*)(g + off);
    }
}

// ---------------- Um1 = U1 @ inv(Um), fp32 Gauss-Jordan (unchanged) ---------
__global__ __launch_bounds__(256) void kraus_invert(
    const float* __restrict__ U1, const float* __restrict__ Um,
    float* __restrict__ Um1) {
  __shared__ float M[64][66];
  __shared__ float X[64][66];
  __shared__ int s_piv;
  int tid = threadIdx.x;
#pragma unroll
  for (int it = 0; it < 16; ++it) {
    int idx = tid + 256 * it;
    int r = idx >> 6, c = idx & 63;
    M[r][c] = Um[idx];
    X[r][c] = (r == c) ? 1.0f : 0.0f;
  }
  __syncthreads();
  for (int k = 0; k < 64; ++k) {
    if (tid < 64) {
      float v = (tid >= k) ? fabsf(M[tid][k]) : -1.0f;
      int idx = tid;
      for (int off = 32; off; off >>= 1) {
        float ov = __shfl_down(v, off);
        int oi = __shfl_down(idx, off);
        if (ov > v) { v = ov; idx = oi; }
      }
      if (tid == 0) s_piv = idx;
    }
    __syncthreads();
    int p = s_piv;
    if (p != k && tid < 64) {
      float t1 = M[k][tid]; M[k][tid] = M[p][tid]; M[p][tid] = t1;
      float t2 = X[k][tid]; X[k][tid] = X[p][tid]; X[p][tid] = t2;
    }
    __syncthreads();
    float inv_pv = 1.0f / M[k][k];
    __syncthreads();
    if (tid < 64) { M[k][tid] *= inv_pv; X[k][tid] *= inv_pv; }
    __syncthreads();
    int r = tid & 63, q = tid >> 6;
    float f = M[r][k];
    __syncthreads();
    if (r != k) {
#pragma unroll
      for (int cc = 0; cc < 16; ++cc) {
        int c = q * 16 + cc;
        M[r][c] -= f * M[k][c];
        X[r][c] -= f * X[k][c];
      }
    }
    __syncthreads();
  }
  for (int it = 0; it < 16; ++it) {
    int idx = tid + 256 * it;
    int i = idx >> 6, j = idx & 63;
    float s = 0.0f;
#pragma unroll 4
    for (int k = 0; k < 64; ++k) s += U1[i * 64 + k] * X[k][j];
    Um1[idx] = s;
  }
}

// ---------------- prepack: 15 operators -> bf16 fragment-major in ws --------
// op order: 0=U1 1=Um 2=Um1 3..6=Ls0 7..10=Lsmid 11..14=Ls1
// frag elem: d[o*4096 + f*512 + l*8 + i] = M[t*32+(l&31)][s*16+(l>>5)*8+i], f=t*4+s
__global__ __launch_bounds__(256) void kraus_prepack(
    const float* __restrict__ U1, const float* __restrict__ Um,
    const float* __restrict__ Ls0, const float* __restrict__ Lsmid,
    const float* __restrict__ Ls1, float* __restrict__ ws) {
  const float* Um1 = ws;
  unsigned short* dst = (unsigned short*)((char*)ws + 16384);
  int o = blockIdx.x;
  const float* s;
  if (o == 0) s = U1;
  else if (o == 1) s = Um;
  else if (o == 2) s = Um1;
  else if (o < 7) s = Ls0 + (o - 3) * 4096;
  else if (o < 11) s = Lsmid + (o - 7) * 4096;
  else s = Ls1 + (o - 11) * 4096;
  unsigned short* d = dst + o * 4096;
  int tid = threadIdx.x;
#pragma unroll
  for (int j = 0; j < 16; ++j) {
    int idx = tid + 256 * j;
    int f = idx >> 9, l = (idx >> 3) & 63, i = idx & 7;
    int t = f >> 2, ss = f & 3;
    int R = t * 32 + (l & 31);
    int C = ss * 16 + (l >> 5) * 8 + i;
    d[idx] = bf16rne(s[R * 64 + C]);
  }
}

// ---------------- main kernel: one block per batch item ---------------------
__global__ __launch_bounds__(256, 2) void kraus_main(
    const float* __restrict__ rho0g, const float* __restrict__ dtp,
    const char* __restrict__ gfrag, float* __restrict__ outg) {
  __shared__ __align__(16) char lds[LDS_TOTAL];
  char* OPA = lds;
  char* B0 = lds + OPA_B;     // hat(rho0) -> hat(J2)
  char* B1 = B0 + MATB;       // hat(J0)->hat(T)->hat(rho2)->hat(rho3)->hat(JJ)
  char* B3 = B1 + MATB;       // hat(S) -> hat(J3)
  char* B4 = B3 + MATB;       // hat(P) -> hat(rho4)
  char* TMP = B4 + MATB;      // plain S / T_k intermediates

  const int tid = threadIdx.x;
  const int l = tid & 63, w = tid >> 6;
  const int ti = w >> 1, tj = w & 1;
  const int l31 = l & 31, lh = l >> 5;
  const int mA = (ti * 32 + l31) * PITCH + lh * 16;   // matrix as P, tile ti
  const int mB = (tj * 32 + l31) * PITCH + lh * 16;   // matrix as Q, tile tj
  const int oA = ti * 4096 + l * 16;                  // operator as P
  const int oB = tj * 4096 + l * 16;                  // operator as Q
  const int woff = (ti * 32 + lh * 4) * PITCH + (tj * 32 + l31) * 2;
  const float dt = dtp[0];
  const size_t b = blockIdx.x;

  // stage hat(rho0): B0[c][r] = rho0[r][c]
  {
    const float* src = rho0g + b * 4096 + tid * 16;
    float vals[16];
#pragma unroll
    for (int q = 0; q < 4; ++q) {
      float4 f = *(const float4*)(src + q * 4);
      vals[q * 4 + 0] = f.x; vals[q * 4 + 1] = f.y;
      vals[q * 4 + 2] = f.z; vals[q * 4 + 3] = f.w;
    }
    int r = tid >> 2, c0 = (tid & 3) * 16;
#pragma unroll
    for (int u = 0; u < 16; ++u)
      *(unsigned short*)(B0 + (c0 + u) * PITCH + r * 2) = bf16rne(vals[u]);
  }
  stage_ops(OPA, gfrag + 3 * 8192, 4, tid);   // Ls0
  __syncthreads();

  f32x16 outacc = {};

  // J0 -> B1 (hat form)
  {
    f32x16 J = {};
    for (int k = 0; k < 4; ++k) {
      if (k) __syncthreads();
      f32x16 t = {};
      mm4(t, OPA + k * 8192 + oA, 1024, B0 + mB, 32);   // T_k = L @ rho0
      wtile(TMP + woff, t);
      __syncthreads();
      mm4(J, OPA + k * 8192 + oA, 1024, TMP + mB, 32);  // hat(J) += L @ T^T
    }
    __syncthreads();
    wtile(B1 + woff, J);
  }
  __syncthreads();
  stage_ops(OPA, gfrag, 2, tid);   // slot0=U1, slot1=Um
  __syncthreads();

  // out += dt/6 * sandwich(U1, J0)
  { f32x16 t = {}; mm4(t, OPA + oA, 1024, B1 + mB, 32); wtile(TMP + woff, t); }
  __syncthreads();
  { f32x16 s = {}; mm4(s, TMP + mA, 32, OPA + oB, 1024); outacc += (dt / 6.f) * s; }
  __syncthreads();

  // P = sandwich(U1, rho0): out += P ; B4 = hat(P)
  { f32x16 t = {}; mm4(t, OPA + oA, 1024, B0 + mB, 32); wtile(TMP + woff, t); }
  __syncthreads();
  { f32x16 s = {}; mm4(s, TMP + mA, 32, OPA + oB, 1024); outacc += s; }
  { f32x16 s = {}; mm4(s, OPA + oA, 1024, TMP + mB, 32); wtile(B4 + woff, s); }

  // hat(T) = hat(rho0) + 0.5dt*hat(J0) -> B1
  axpy(B1, B0, 0.5f * dt, B1, tid);
  __syncthreads();

  // hat(rho2) = hat(sandwich(Um, T)) -> B1   (Um = slot1)
  { f32x16 t = {}; mm4(t, OPA + 8192 + oA, 1024, B1 + mB, 32); wtile(TMP + woff, t); }
  __syncthreads();
  { f32x16 s = {}; mm4(s, OPA + 8192 + oA, 1024, TMP + mB, 32); wtile(B1 + woff, s); }
  __syncthreads();

  // hat(S) = hat(sandwich(Um, rho0)) -> B3
  { f32x16 t = {}; mm4(t, OPA + 8192 + oA, 1024, B0 + mB, 32); wtile(TMP + woff, t); }
  __syncthreads();
  { f32x16 s = {}; mm4(s, OPA + 8192 + oA, 1024, TMP + mB, 32); wtile(B3 + woff, s); }
  __syncthreads();
  stage_ops(OPA, gfrag + 7 * 8192, 4, tid);   // Lsmid
  __syncthreads();

  // J2 -> B0 (rho0 dead)
  {
    f32x16 J = {};
    for (int k = 0; k < 4; ++k) {
      if (k) __syncthreads();
      f32x16 t = {};
      mm4(t, OPA + k * 8192 + oA, 1024, B1 + mB, 32);   // L @ rho2
      wtile(TMP + woff, t);
      __syncthreads();
      mm4(J, OPA + k * 8192 + oA, 1024, TMP + mB, 32);
    }
    __syncthreads();
    wtile(B0 + woff, J);
  }
  __syncthreads();
  // hat(rho3) = hat(S) + 0.5dt*hat(J2) -> B1
  axpy(B1, B3, 0.5f * dt, B0, tid);
  __syncthreads();

  // J3 -> B3 (S dead)
  {
    f32x16 J = {};
    for (int k = 0; k < 4; ++k) {
      if (k) __syncthreads();
      f32x16 t = {};
      mm4(t, OPA + k * 8192 + oA, 1024, B1 + mB, 32);   // L @ rho3
      wtile(TMP + woff, t);
      __syncthreads();
      mm4(J, OPA + k * 8192 + oA, 1024, TMP + mB, 32);
    }
    __syncthreads();
    wtile(B3 + woff, J);
  }
  __syncthreads();
  // hat(JJ) = hat(J2) + hat(J3) -> B1 (rho3 dead)
  axpy(B1, B0, 1.0f, B3, tid);
  __syncthreads();
  stage_ops(OPA, gfrag + 2 * 8192, 1, tid);   // Um1 -> slot0
  __syncthreads();

  // out += dt/3 * sandwich(Um1, JJ)
  { f32x16 t = {}; mm4(t, OPA + oA, 1024, B1 + mB, 32); wtile(TMP + woff, t); }
  __syncthreads();
  { f32x16 s = {}; mm4(s, TMP + mA, 32, OPA + oB, 1024); outacc += (dt / 3.f) * s; }
  __syncthreads();

  // hat(rho4) = hat(P) + dt * hat(sandwich(Um1, J3)) -> B4 (RMW own tile)
  { f32x16 t = {}; mm4(t, OPA + oA, 1024, B3 + mB, 32); wtile(TMP + woff, t); }
  __syncthreads();
  { f32x16 s = {}; mm4(s, OPA + oA, 1024, TMP + mB, 32); wtile_rmw(B4 + woff, s, dt); }
  __syncthreads();
  stage_ops(OPA, gfrag + 11 * 8192, 4, tid);  // Ls1
  __syncthreads();

  // out += dt/6 * jump(Ls1, rho4)  (PLAIN form: T_k @ L_k^T)
  {
    f32x16 J = {};
    for (int k = 0; k < 4; ++k) {
      if (k) __syncthreads();
      f32x16 t = {};
      mm4(t, OPA + k * 8192 + oA, 1024, B4 + mB, 32);   // L @ rho4
      wtile(TMP + woff, t);
      __syncthreads();
      mm4(J, TMP + mA, 32, OPA + k * 8192 + oB, 1024);  // plain: T @ L^T
    }
    outacc += (dt / 6.f) * J;
  }

  // store fp32 output tile
  {
    float* op = outg + b * 4096 + (size_t)(ti * 32 + lh * 4) * 64 + tj * 32 + l31;
#pragma unroll
    for (int r = 0; r < 16; ++r) {
      int row = (r & 3) + 8 * (r >> 2);
      op[row * 64] = outacc[r];
    }
  }
}

extern "C" void kernel_launch(void* const* d_in, const int* in_sizes, int n_in,
                              void* d_out, int out_size, void* d_ws, size_t ws_size,
                              hipStream_t stream) {
  const float* rho0 = (const float*)d_in[0];
  const float* U1 = (const float*)d_in[1];
  const float* Um = (const float*)d_in[2];
  const float* Ls0 = (const float*)d_in[3];
  const float* Lsmid = (const float*)d_in[4];
  const float* Ls1 = (const float*)d_in[5];
  const float* dtp = (const float*)d_in[6];
  float* out = (float*)d_out;
  float* ws = (float*)d_ws;            // [0,16KB): Um1 fp32; [16KB,136KB): frags

  const int B = in_sizes[0] >> 12;

  kraus_invert<<<1, 256, 0, stream>>>(U1, Um, ws);
  kraus_prepack<<<15, 256, 0, stream>>>(U1, Um, Ls0, Lsmid, Ls1, ws);
  kraus_main<<<B, 256, 0, stream>>>(rho0, dtp, (const char*)d_ws + 16384, out);
}

// Round 4
// 232.575 us; speedup vs baseline: 8.3829x; 1.1083x over previous
//
#include <hip/hip_runtime.h>

// KrausRK4 via bf16 MFMA, r4: operators read direct from global (L2),
// LDS = 5 x 8KB swizzled matrices -> 4 blocks/CU, no staging phases.
// phys(row, cbyte) = row*128 + (((cbyte>>4) ^ ((row>>3)&7))<<4) + (cbyte&15)

typedef __attribute__((ext_vector_type(16))) float f32x16;
typedef __attribute__((ext_vector_type(8))) __bf16 bf16x8;

#define MATB 8192

__device__ __forceinline__ unsigned short bf16rne(float x) {
  unsigned u = __builtin_bit_cast(unsigned, x);
  return (unsigned short)((u + 0x7FFFu + ((u >> 16) & 1u)) >> 16);
}
__device__ __forceinline__ float bflo(unsigned u) {
  return __builtin_bit_cast(float, u << 16);
}
__device__ __forceinline__ float bfhi(unsigned u) {
  return __builtin_bit_cast(float, u & 0xFFFF0000u);
}

// acc += P @ Q^T, P = operator frags (global), Q = LDS matrix rows (swizzled)
__device__ __forceinline__ void mm4_gl(f32x16& acc, const char* __restrict__ gP,
                                       const char* ldsQ, int vq, int lh) {
#pragma unroll
  for (int s = 0; s < 4; ++s) {
    bf16x8 a = *(const bf16x8*)(gP + s * 1024);
    bf16x8 b = *(const bf16x8*)(ldsQ + (((2 * s + lh) ^ vq) << 4));
    acc = __builtin_amdgcn_mfma_f32_32x32x16_bf16(a, b, acc, 0, 0, 0);
  }
}
// acc += P @ Q^T, P = LDS matrix rows (swizzled), Q = operator frags (global)
__device__ __forceinline__ void mm4_lg(f32x16& acc, const char* ldsP, int vp,
                                       int lh, const char* __restrict__ gQ) {
#pragma unroll
  for (int s = 0; s < 4; ++s) {
    bf16x8 a = *(const bf16x8*)(ldsP + (((2 * s + lh) ^ vp) << 4));
    bf16x8 b = *(const bf16x8*)(gQ + s * 1024);
    acc = __builtin_amdgcn_mfma_f32_32x32x16_bf16(a, b, acc, 0, 0, 0);
  }
}

// write 32x32 C-tile (row-major, swizzled): row = ti*32+4lh+(r&3)+8(r>>2)
__device__ __forceinline__ void wtile(char* base, int ti, int slotc, int coff,
                                      int lh, const f32x16& v) {
#pragma unroll
  for (int r = 0; r < 16; ++r) {
    int row = ti * 32 + 4 * lh + (r & 3) + 8 * (r >> 2);
    int ps = (slotc ^ ((4 * ti + (r >> 2)) & 7)) << 4;
    *(unsigned short*)(base + row * 128 + ps + coff) = bf16rne(v[r]);
  }
}
__device__ __forceinline__ void wtile_rmw(char* base, int ti, int slotc, int coff,
                                          int lh, const f32x16& v, float s) {
#pragma unroll
  for (int r = 0; r < 16; ++r) {
    int row = ti * 32 + 4 * lh + (r & 3) + 8 * (r >> 2);
    int ps = (slotc ^ ((4 * ti + (r >> 2)) & 7)) << 4;
    unsigned short* p = (unsigned short*)(base + row * 128 + ps + coff);
    float old = bflo((unsigned)*p);
    *p = bf16rne(old + s * v[r]);
  }
}

// D = A + s*B elementwise on raw swizzled dwords (2048 per matrix)
__device__ __forceinline__ void axpy(char* D, const char* A, float s,
                                     const char* B, int tid) {
#pragma unroll
  for (int j = 0; j < 8; ++j) {
    int off = (tid + 256 * j) * 4;
    unsigned a = *(const unsigned*)(A + off);
    unsigned b = *(const unsigned*)(B + off);
    float lo = bflo(a) + s * bflo(b);
    float hi = bfhi(a) + s * bfhi(b);
    *(unsigned*)(D + off) = (unsigned)bf16rne(lo) | ((unsigned)bf16rne(hi) << 16);
  }
}

// ---------------- Um1 = U1 @ inv(Um), fp32 Gauss-Jordan, no pivot -----------
__global__ __launch_bounds__(256) void kraus_invert(
    const float* __restrict__ U1, const float* __restrict__ Um,
    float* __restrict__ Um1) {
  __shared__ float M[64][66];
  __shared__ float X[64][66];
  int tid = threadIdx.x;
#pragma unroll
  for (int it = 0; it < 16; ++it) {
    int idx = tid + 256 * it;
    int r = idx >> 6, c = idx & 63;
    M[r][c] = Um[idx];
    X[r][c] = (r == c) ? 1.0f : 0.0f;
  }
  __syncthreads();
  for (int k = 0; k < 64; ++k) {
    if (tid < 64) {
      float ip = 1.0f / M[k][k];   // all lanes read before lane k writes
      M[k][tid] *= ip;
      X[k][tid] *= ip;
    }
    __syncthreads();
    int r = tid & 63, q = tid >> 6;
    float f = M[r][k];
    __syncthreads();
    if (r != k) {
#pragma unroll
      for (int cc = 0; cc < 16; ++cc) {
        int c = q * 16 + cc;
        M[r][c] -= f * M[k][c];
        X[r][c] -= f * X[k][c];
      }
    }
    __syncthreads();
  }
  for (int it = 0; it < 16; ++it) {
    int idx = tid + 256 * it;
    int i = idx >> 6, j = idx & 63;
    float s = 0.0f;
#pragma unroll 4
    for (int k = 0; k < 64; ++k) s += U1[i * 64 + k] * X[k][j];
    Um1[idx] = s;
  }
}

// ---------------- prepack: 15 operators -> bf16 fragment-major in ws --------
// op order: 0=U1 1=Um 2=Um1 3..6=Ls0 7..10=Lsmid 11..14=Ls1
// frag elem: d[o*4096 + f*512 + l*8 + i] = M[t*32+(l&31)][s*16+(l>>5)*8+i], f=t*4+s
__global__ __launch_bounds__(256) void kraus_prepack(
    const float* __restrict__ U1, const float* __restrict__ Um,
    const float* __restrict__ Ls0, const float* __restrict__ Lsmid,
    const float* __restrict__ Ls1, float* __restrict__ ws) {
  const float* Um1 = ws;
  unsigned short* dst = (unsigned short*)((char*)ws + 16384);
  int o = blockIdx.x;
  const float* s;
  if (o == 0) s = U1;
  else if (o == 1) s = Um;
  else if (o == 2) s = Um1;
  else if (o < 7) s = Ls0 + (o - 3) * 4096;
  else if (o < 11) s = Lsmid + (o - 7) * 4096;
  else s = Ls1 + (o - 11) * 4096;
  unsigned short* d = dst + o * 4096;
  int tid = threadIdx.x;
#pragma unroll
  for (int j = 0; j < 16; ++j) {
    int idx = tid + 256 * j;
    int f = idx >> 9, l = (idx >> 3) & 63, i = idx & 7;
    int t = f >> 2, ss = f & 3;
    int R = t * 32 + (l & 31);
    int C = ss * 16 + (l >> 5) * 8 + i;
    d[idx] = bf16rne(s[R * 64 + C]);
  }
}

// ---------------- main kernel: one block per batch item ---------------------
__global__ __launch_bounds__(256, 4) void kraus_main(
    const float* __restrict__ rho0g, const float* __restrict__ dtp,
    const char* __restrict__ gfrag, float* __restrict__ outg) {
  __shared__ __align__(16) char lds[5 * MATB];   // 40960 B -> 4 blocks/CU
  char* B0 = lds;              // hat(rho0) -> hat(J2)
  char* B1 = B0 + MATB;        // hat(J0)->hat(T)->hat(rho2)->hat(rho3)->hat(JJ)
  char* B3 = B1 + MATB;        // hat(S) -> hat(J3)
  char* B4 = B3 + MATB;        // hat(P) -> hat(rho4)
  char* TMP = B4 + MATB;       // plain T intermediates

  const int tid = threadIdx.x;
  const int l = tid & 63, w = tid >> 6;
  const int ti = w >> 1, tj = w & 1;
  const int l31 = l & 31, lh = l >> 5;
  const int vA = (4 * ti + (l31 >> 3)) & 7;   // swizzle key, P-side rows
  const int vB = (4 * tj + (l31 >> 3)) & 7;   // swizzle key, Q-side rows
  const int rA = (ti * 32 + l31) * 128;
  const int rB = (tj * 32 + l31) * 128;
  const int slotc = 4 * tj + (l31 >> 3), coff = (l31 & 7) * 2;
  const float dt = dtp[0];
  const size_t b = blockIdx.x;
  const char* gA0 = gfrag + ti * 4096 + l * 16;   // + op*8192 : P-operand frags
  const char* gB0 = gfrag + tj * 4096 + l * 16;   // + op*8192 : Q-operand frags
#define GA(o) (gA0 + (o) * 8192)
#define GB(o) (gB0 + (o) * 8192)

  // stage hat(rho0): B0[c][r] = rho0[r][c], swizzled
  {
    const float* src = rho0g + b * 4096 + tid * 16;
    float vals[16];
#pragma unroll
    for (int q = 0; q < 4; ++q) {
      float4 f = *(const float4*)(src + q * 4);
      vals[q * 4 + 0] = f.x; vals[q * 4 + 1] = f.y;
      vals[q * 4 + 2] = f.z; vals[q * 4 + 3] = f.w;
    }
    int r = tid >> 2, c0 = (tid & 3) * 16;
    int sr = r >> 3, cr = (r & 7) * 2;
#pragma unroll
    for (int u = 0; u < 16; ++u) {
      int row = c0 + u;
      int ps = (sr ^ ((row >> 3) & 7)) << 4;
      *(unsigned short*)(B0 + row * 128 + ps + cr) = bf16rne(vals[u]);
    }
  }
  __syncthreads();

  f32x16 outacc = {};

  // J0 -> B1 (hat form), Ls0 = ops 3..6
  {
    f32x16 J = {};
    for (int k = 0; k < 4; ++k) {
      if (k) __syncthreads();
      f32x16 t = {};
      mm4_gl(t, GA(3 + k), B0 + rB, vB, lh);        // T = L @ rho0
      wtile(TMP, ti, slotc, coff, lh, t);
      __syncthreads();
      mm4_gl(J, GA(3 + k), TMP + rB, vB, lh);       // hat(J) += L @ T^T
    }
    __syncthreads();
    wtile(B1, ti, slotc, coff, lh, J);
  }
  __syncthreads();

  // out += dt/6 * sandwich(U1, J0)
  { f32x16 t = {}; mm4_gl(t, GA(0), B1 + rB, vB, lh); wtile(TMP, ti, slotc, coff, lh, t); }
  __syncthreads();
  { f32x16 s = {}; mm4_lg(s, TMP + rA, vA, lh, GB(0)); outacc += (dt / 6.f) * s; }
  __syncthreads();

  // P = sandwich(U1, rho0): out += P ; B4 = hat(P)
  { f32x16 t = {}; mm4_gl(t, GA(0), B0 + rB, vB, lh); wtile(TMP, ti, slotc, coff, lh, t); }
  __syncthreads();
  { f32x16 s = {}; mm4_lg(s, TMP + rA, vA, lh, GB(0)); outacc += s; }
  { f32x16 s = {}; mm4_gl(s, GA(0), TMP + rB, vB, lh); wtile(B4, ti, slotc, coff, lh, s); }

  // hat(T) = hat(rho0) + 0.5dt*hat(J0) -> B1
  axpy(B1, B0, 0.5f * dt, B1, tid);
  __syncthreads();

  // hat(rho2) = hat(sandwich(Um, T)) -> B1   (Um = op 1)
  { f32x16 t = {}; mm4_gl(t, GA(1), B1 + rB, vB, lh); wtile(TMP, ti, slotc, coff, lh, t); }
  __syncthreads();
  { f32x16 s = {}; mm4_gl(s, GA(1), TMP + rB, vB, lh); wtile(B1, ti, slotc, coff, lh, s); }
  __syncthreads();

  // hat(S) = hat(sandwich(Um, rho0)) -> B3
  { f32x16 t = {}; mm4_gl(t, GA(1), B0 + rB, vB, lh); wtile(TMP, ti, slotc, coff, lh, t); }
  __syncthreads();
  { f32x16 s = {}; mm4_gl(s, GA(1), TMP + rB, vB, lh); wtile(B3, ti, slotc, coff, lh, s); }
  __syncthreads();

  // J2 -> B0 (rho0 dead), Lsmid = ops 7..10
  {
    f32x16 J = {};
    for (int k = 0; k < 4; ++k) {
      if (k) __syncthreads();
      f32x16 t = {};
      mm4_gl(t, GA(7 + k), B1 + rB, vB, lh);        // L @ rho2
      wtile(TMP, ti, slotc, coff, lh, t);
      __syncthreads();
      mm4_gl(J, GA(7 + k), TMP + rB, vB, lh);
    }
    __syncthreads();
    wtile(B0, ti, slotc, coff, lh, J);
  }
  __syncthreads();
  // hat(rho3) = hat(S) + 0.5dt*hat(J2) -> B1
  axpy(B1, B3, 0.5f * dt, B0, tid);
  __syncthreads();

  // J3 -> B3 (S dead)
  {
    f32x16 J = {};
    for (int k = 0; k < 4; ++k) {
      if (k) __syncthreads();
      f32x16 t = {};
      mm4_gl(t, GA(7 + k), B1 + rB, vB, lh);        // L @ rho3
      wtile(TMP, ti, slotc, coff, lh, t);
      __syncthreads();
      mm4_gl(J, GA(7 + k), TMP + rB, vB, lh);
    }
    __syncthreads();
    wtile(B3, ti, slotc, coff, lh, J);
  }
  __syncthreads();
  // hat(JJ) = hat(J2) + hat(J3) -> B1
  axpy(B1, B0, 1.0f, B3, tid);
  __syncthreads();

  // out += dt/3 * sandwich(Um1, JJ)   (Um1 = op 2)
  { f32x16 t = {}; mm4_gl(t, GA(2), B1 + rB, vB, lh); wtile(TMP, ti, slotc, coff, lh, t); }
  __syncthreads();
  { f32x16 s = {}; mm4_lg(s, TMP + rA, vA, lh, GB(2)); outacc += (dt / 3.f) * s; }
  __syncthreads();

  // hat(rho4) = hat(P) + dt * hat(sandwich(Um1, J3)) -> B4
  { f32x16 t = {}; mm4_gl(t, GA(2), B3 + rB, vB, lh); wtile(TMP, ti, slotc, coff, lh, t); }
  __syncthreads();
  { f32x16 s = {}; mm4_gl(s, GA(2), TMP + rB, vB, lh); wtile_rmw(B4, ti, slotc, coff, lh, s, dt); }
  __syncthreads();

  // out += dt/6 * jump(Ls1, rho4), plain form; Ls1 = ops 11..14
  {
    f32x16 J = {};
    for (int k = 0; k < 4; ++k) {
      if (k) __syncthreads();
      f32x16 t = {};
      mm4_gl(t, GA(11 + k), B4 + rB, vB, lh);       // L @ rho4
      wtile(TMP, ti, slotc, coff, lh, t);
      __syncthreads();
      mm4_lg(J, TMP + rA, vA, lh, GB(11 + k));      // plain: T @ L^T
    }
    outacc += (dt / 6.f) * J;
  }

  // store fp32 output tile
  {
    float* op = outg + b * 4096 + (size_t)(ti * 32 + lh * 4) * 64 + tj * 32 + l31;
#pragma unroll
    for (int r = 0; r < 16; ++r) {
      int row = (r & 3) + 8 * (r >> 2);
      op[row * 64] = outacc[r];
    }
  }
#undef GA
#undef GB
}

extern "C" void kernel_launch(void* const* d_in, const int* in_sizes, int n_in,
                              void* d_out, int out_size, void* d_ws, size_t ws_size,
                              hipStream_t stream) {
  const float* rho0 = (const float*)d_in[0];
  const float* U1 = (const float*)d_in[1];
  const float* Um = (const float*)d_in[2];
  const float* Ls0 = (const float*)d_in[3];
  const float* Lsmid = (const float*)d_in[4];
  const float* Ls1 = (const float*)d_in[5];
  const float* dtp = (const float*)d_in[6];
  float* out = (float*)d_out;
  float* ws = (float*)d_ws;   // [0,16KB): Um1 fp32; [16KB,136KB): bf16 frags

  const int B = in_sizes[0] >> 12;

  kraus_invert<<<1, 256, 0, stream>>>(U1, Um, ws);
  kraus_prepack<<<15, 256, 0, stream>>>(U1, Um, Ls0, Lsmid, Ls1, ws);
  kraus_main<<<B, 256, 0, stream>>>(rho0, dtp, (const char*)d_ws + 16384, out);
}